// Round 7
// baseline (402.467 us; speedup 1.0000x reference)
//
#include <hip/hip_runtime.h>
#include <math.h>

// Problem: N=8192 nodes, D=256 features, H=64 hidden.
// out = [h_out (N*D floats), e (N floats)] concatenated, fp32.
// ws layout: g (N*256 bf16 = 4 MB) | idx (N*256 u16 = 4 MB) | cnt (N int)

typedef float nfloat4 __attribute__((ext_vector_type(4)));

__device__ inline float bf16_to_f32(unsigned short s) {
    union { unsigned u; float f; } c; c.u = ((unsigned)s) << 16; return c.f;
}
__device__ inline unsigned short f32_to_bf16(float f) {   // RNE, finite inputs
    union { float f; unsigned u; } c; c.f = f;
    unsigned r = c.u + 0x7FFFu + ((c.u >> 16) & 1u);
    return (unsigned short)(r >> 16);
}

// ---------------- Kernel 1: gate + bf16 pre-scale ----------------------------
__global__ __launch_bounds__(256) void gate_kernel(const float* __restrict__ h,
                                                   const float* __restrict__ W1,
                                                   const float* __restrict__ b1,
                                                   const float* __restrict__ W2,
                                                   const float* __restrict__ b2,
                                                   float* __restrict__ e_out,
                                                   unsigned short* __restrict__ g_out,
                                                   int N) {
    __shared__ float W1s[256 * 64];            // 64 KB
    const int tid = threadIdx.x;

    const float4* W1v = reinterpret_cast<const float4*>(W1);
    float4* W1sv = reinterpret_cast<float4*>(W1s);
    #pragma unroll
    for (int t = 0; t < 16; ++t) W1sv[tid + 256 * t] = W1v[tid + 256 * t];
    __syncthreads();

    const int wave = tid >> 6;
    const int k    = tid & 63;
    const float b1k = b1[k];
    const float w2k = W2[k];
    const float b2v = b2[0];

    const int base = blockIdx.x * 16;
    for (int r = wave; r < 16; r += 4) {
        const int i = base + r;
        if (i >= N) break;
        const float4* hv = reinterpret_cast<const float4*>(h + (size_t)i * 256);
        float acc = 0.f;
        #pragma unroll 4
        for (int d4 = 0; d4 < 64; ++d4) {
            float4 a = hv[d4];
            const int d = d4 * 4;
            acc = fmaf(a.x, W1s[(d + 0) * 64 + k], acc);
            acc = fmaf(a.y, W1s[(d + 1) * 64 + k], acc);
            acc = fmaf(a.z, W1s[(d + 2) * 64 + k], acc);
            acc = fmaf(a.w, W1s[(d + 3) * 64 + k], acc);
        }
        float v = fmaxf(acc + b1k, 0.f) * w2k;
        #pragma unroll
        for (int off = 32; off > 0; off >>= 1) v += __shfl_down(v, off);
        float vs = __shfl(v, 0);
        float ev = 1.f / (1.f + expf(-(vs + b2v)));
        if (k == 0) e_out[i] = ev;
        float4 hr = hv[k];
        ushort4 p;
        p.x = f32_to_bf16(ev * hr.x);
        p.y = f32_to_bf16(ev * hr.y);
        p.z = f32_to_bf16(ev * hr.z);
        p.w = f32_to_bf16(ev * hr.w);
        reinterpret_cast<ushort4*>(g_out + (size_t)i * 256)[k] = p;
    }
}

// ---------------- Kernel 2a: pure A-scan -> per-row column lists -------------
// Wave per row, prefetch depth 4 NT loads (pure stream, no dependent gathers).
// Ballot + prefix-popcount compaction; count lives in an SGPR (wave owns row).
__global__ __launch_bounds__(256) void scan_kernel(const float* __restrict__ A,
                                                   unsigned short* __restrict__ idx,
                                                   int* __restrict__ cnt,
                                                   int N) {
    const int tid  = threadIdx.x;
    const int lane = tid & 63;
    const int i    = blockIdx.x * 4 + (tid >> 6);
    if (i >= N) return;

    const nfloat4* Arow = reinterpret_cast<const nfloat4*>(A + (size_t)i * N);
    unsigned short* rb = idx + (size_t)i * 256;
    const unsigned long long below = (lane == 63) ? ~0ull >> 1
                                                  : (1ull << lane) - 1;

    const int groups = N / 256;                 // 32, multiple of 4
    nfloat4 q0 = __builtin_nontemporal_load(&Arow[0 * 64 + lane]);
    nfloat4 q1 = __builtin_nontemporal_load(&Arow[1 * 64 + lane]);
    nfloat4 q2 = __builtin_nontemporal_load(&Arow[2 * 64 + lane]);
    nfloat4 q3 = __builtin_nontemporal_load(&Arow[3 * 64 + lane]);

    int count = 0;                              // wave-uniform
    for (int gi = 0; gi < groups; gi += 4) {
        nfloat4 c0 = q0, c1 = q1, c2 = q2, c3 = q3;
        if (gi + 4 < groups) {
            q0 = __builtin_nontemporal_load(&Arow[(gi + 4) * 64 + lane]);
            q1 = __builtin_nontemporal_load(&Arow[(gi + 5) * 64 + lane]);
            q2 = __builtin_nontemporal_load(&Arow[(gi + 6) * 64 + lane]);
            q3 = __builtin_nontemporal_load(&Arow[(gi + 7) * 64 + lane]);
        }
        #pragma unroll
        for (int u = 0; u < 4; ++u) {
            nfloat4 a4 = (u == 0) ? c0 : (u == 1) ? c1 : (u == 2) ? c2 : c3;
            const int colbase = (gi + u) * 256 + 4 * lane;
            #pragma unroll
            for (int s = 0; s < 4; ++s) {
                float av = (s == 0) ? a4.x : (s == 1) ? a4.y : (s == 2) ? a4.z : a4.w;
                unsigned long long m = __ballot(av > 0.f);
                if (av > 0.f) {
                    int pos = count + __popcll(m & below);
                    if (pos < 256) rb[pos] = (unsigned short)(colbase + s);
                }
                count += __popcll(m);
            }
        }
    }
    if (lane == 0) cnt[i] = (count < 256) ? count : 256;
}

// ---------------- Kernel 2b: gather h_out[i,:] = sum g[idx[i,p],:] -----------
// Wave per row; 8 independent 512 B g-row gathers in flight per iteration;
// index words pipelined one ahead. No A loads -> no in-order vmcnt coupling.
__global__ __launch_bounds__(256) void gather_kernel(const unsigned short* __restrict__ idx,
                                                     const int* __restrict__ cnt,
                                                     const unsigned short* __restrict__ g,
                                                     float* __restrict__ h_out,
                                                     int N) {
    const int tid  = threadIdx.x;
    const int lane = tid & 63;
    const int i    = blockIdx.x * 4 + (tid >> 6);
    if (i >= N) return;

    const int c = cnt[i];
    const ushort4* gv  = reinterpret_cast<const ushort4*>(g);       // g[j] row = gv[j*64+lane]
    const unsigned short* rb = idx + (size_t)i * 256;
    const uint4* rbw = reinterpret_cast<const uint4*>(rb);          // 8 u16 per uint4

    float4 acc = {0.f, 0.f, 0.f, 0.f};
    int p = 0;
    uint4 iw = (c >= 8) ? rbw[0] : make_uint4(0, 0, 0, 0);
    for (; p + 8 <= c; p += 8) {
        uint4 iw_next;
        if (p + 16 <= c) iw_next = rbw[(p >> 3) + 1];
        const int j0 = iw.x & 0xFFFF, j1 = iw.x >> 16;
        const int j2 = iw.y & 0xFFFF, j3 = iw.y >> 16;
        const int j4 = iw.z & 0xFFFF, j5 = iw.z >> 16;
        const int j6 = iw.w & 0xFFFF, j7 = iw.w >> 16;
        ushort4 g0 = gv[(size_t)j0 * 64 + lane];
        ushort4 g1 = gv[(size_t)j1 * 64 + lane];
        ushort4 g2 = gv[(size_t)j2 * 64 + lane];
        ushort4 g3 = gv[(size_t)j3 * 64 + lane];
        ushort4 g4 = gv[(size_t)j4 * 64 + lane];
        ushort4 g5 = gv[(size_t)j5 * 64 + lane];
        ushort4 g6 = gv[(size_t)j6 * 64 + lane];
        ushort4 g7 = gv[(size_t)j7 * 64 + lane];
        acc.x += bf16_to_f32(g0.x); acc.y += bf16_to_f32(g0.y); acc.z += bf16_to_f32(g0.z); acc.w += bf16_to_f32(g0.w);
        acc.x += bf16_to_f32(g1.x); acc.y += bf16_to_f32(g1.y); acc.z += bf16_to_f32(g1.z); acc.w += bf16_to_f32(g1.w);
        acc.x += bf16_to_f32(g2.x); acc.y += bf16_to_f32(g2.y); acc.z += bf16_to_f32(g2.z); acc.w += bf16_to_f32(g2.w);
        acc.x += bf16_to_f32(g3.x); acc.y += bf16_to_f32(g3.y); acc.z += bf16_to_f32(g3.z); acc.w += bf16_to_f32(g3.w);
        acc.x += bf16_to_f32(g4.x); acc.y += bf16_to_f32(g4.y); acc.z += bf16_to_f32(g4.z); acc.w += bf16_to_f32(g4.w);
        acc.x += bf16_to_f32(g5.x); acc.y += bf16_to_f32(g5.y); acc.z += bf16_to_f32(g5.z); acc.w += bf16_to_f32(g5.w);
        acc.x += bf16_to_f32(g6.x); acc.y += bf16_to_f32(g6.y); acc.z += bf16_to_f32(g6.z); acc.w += bf16_to_f32(g6.w);
        acc.x += bf16_to_f32(g7.x); acc.y += bf16_to_f32(g7.y); acc.z += bf16_to_f32(g7.z); acc.w += bf16_to_f32(g7.w);
        iw = iw_next;
    }
    for (; p < c; ++p) {
        int j = rb[p];
        ushort4 gj = gv[(size_t)j * 64 + lane];
        acc.x += bf16_to_f32(gj.x); acc.y += bf16_to_f32(gj.y);
        acc.z += bf16_to_f32(gj.z); acc.w += bf16_to_f32(gj.w);
    }

    nfloat4 r; r.x = acc.x; r.y = acc.y; r.z = acc.z; r.w = acc.w;
    nfloat4* outv = reinterpret_cast<nfloat4*>(h_out + (size_t)i * 256);
    __builtin_nontemporal_store(r, &outv[lane]);
}

extern "C" void kernel_launch(void* const* d_in, const int* in_sizes, int n_in,
                              void* d_out, int out_size, void* d_ws, size_t ws_size,
                              hipStream_t stream) {
    const float* A  = (const float*)d_in[0];   // [N, N]
    const float* h  = (const float*)d_in[1];   // [N, D]
    const float* W1 = (const float*)d_in[2];   // [D, H]
    const float* b1 = (const float*)d_in[3];   // [H]
    const float* W2 = (const float*)d_in[4];   // [H, 1]
    const float* b2 = (const float*)d_in[5];   // [1]

    const int H = in_sizes[3];                 // 64
    const int D = in_sizes[2] / H;             // 256
    const int N = in_sizes[1] / D;             // 8192

    float* out   = (float*)d_out;
    float* h_out = out;                        // N*D
    float* e_out = out + (size_t)N * D;        // N

    unsigned char* ws = (unsigned char*)d_ws;
    unsigned short* g_buf   = (unsigned short*)ws;                         // 4 MB
    unsigned short* idx_buf = (unsigned short*)(ws + (size_t)N * D * 2);   // 4 MB
    int*            cnt_buf = (int*)(ws + (size_t)N * D * 4);              // 32 KB

    scan_kernel<<<(N + 3) / 4, 256, 0, stream>>>(A, idx_buf, cnt_buf, N);
    gate_kernel<<<(N + 15) / 16, 256, 0, stream>>>(h, W1, b1, W2, b2, e_out, g_buf, N);
    gather_kernel<<<(N + 3) / 4, 256, 0, stream>>>(idx_buf, cnt_buf, g_buf, h_out, N);
}